// Round 7
// baseline (278.018 us; speedup 1.0000x reference)
//
#include <hip/hip_runtime.h>
#include <stdint.h>
#include <math.h>

#define BB 2
#define TT 2048
#define CC 1024
#define NH 16
#define HD 64
#define N3 (3*CC)
#define NT (TT/64)
#define SPAD 74         // LDS row stride for 16x16-path kernels
#define NSLOT 40        // split-K slots per (b,h): sum of nch(bx), bx=0..15

typedef __attribute__((ext_vector_type(8)))  short bf16x8;
typedef __attribute__((ext_vector_type(4)))  float f32x4;
typedef __attribute__((ext_vector_type(16))) float f32x16;

__device__ inline ushort f2bf(float f) {
  uint32_t u = __float_as_uint(f);
  u += 0x7fff + ((u >> 16) & 1);          // RNE
  return (ushort)(u >> 16);
}
__device__ inline float bf2f(ushort u) {
  return __uint_as_float(((uint32_t)u) << 16);
}
__device__ inline uint32_t cvt_pk_bf16(float lo, float hi_) {
  uint32_t r;
  asm("v_cvt_pk_bf16_f32 %0, %1, %2" : "=v"(r) : "v"(lo), "v"(hi_));
  return r;
}

typedef union { uint32_t u[4]; bf16x8 v; } pack4_t;

// ---------------- cast f32 -> bf16, vectorized ----------------
__global__ __launch_bounds__(256) void cast_bf16_k(const float* __restrict__ in,
                                                   ushort* __restrict__ out, int n)
{
  int i = (blockIdx.x * 256 + threadIdx.x) * 4;
  if (i + 3 < n) {
    float4 v = *(const float4*)(in + i);
    ushort4 o;
    o.x = f2bf(v.x); o.y = f2bf(v.y); o.z = f2bf(v.z); o.w = f2bf(v.w);
    *(ushort4*)(out + i) = o;
  }
}

// ---------------- bf16 MFMA GEMM: C[M,N] = A[M,K] @ W[N,K]^T + bias --------
#define GLDK 40

template<bool OUT_BF16>
__global__ __launch_bounds__(256) void gemm_mfma(
    const ushort* __restrict__ A, const ushort* __restrict__ W,
    const float* __restrict__ bias, void* __restrict__ Cout,
    int M, int N, int K)
{
  __shared__ ushort As[128 * GLDK];
  __shared__ ushort Ws[128 * GLDK];
  const int tid = threadIdx.x;
  const int lane = tid & 63, wave = tid >> 6;
  const int wr = (wave >> 1) * 64, wc = (wave & 1) * 64;
  const int bm = blockIdx.y * 128, bn = blockIdx.x * 128;
  const int fr = lane & 15, kg = (lane >> 4) * 8, rg = (lane >> 4) * 4;
  const int srow = tid >> 1, skb = (tid & 1) * 16;
  f32x4 acc[4][4];
  #pragma unroll
  for (int i=0;i<4;++i)
    #pragma unroll
    for (int j=0;j<4;++j) acc[i][j]=(f32x4){0.f,0.f,0.f,0.f};

  const ushort* ag = A + (size_t)(bm + srow) * K + skb;
  const ushort* wg = W + (size_t)(bn + srow) * K + skb;
  for (int k0 = 0; k0 < K; k0 += 32) {
    bf16x8 a0 = *(const bf16x8*)(ag + k0);
    bf16x8 a1 = *(const bf16x8*)(ag + k0 + 8);
    bf16x8 w0 = *(const bf16x8*)(wg + k0);
    bf16x8 w1 = *(const bf16x8*)(wg + k0 + 8);
    __syncthreads();
    *(bf16x8*)&As[srow * GLDK + skb]     = a0;
    *(bf16x8*)&As[srow * GLDK + skb + 8] = a1;
    *(bf16x8*)&Ws[srow * GLDK + skb]     = w0;
    *(bf16x8*)&Ws[srow * GLDK + skb + 8] = w1;
    __syncthreads();
    bf16x8 af[4], wf[4];
    #pragma unroll
    for (int m = 0; m < 4; ++m) af[m] = *(const bf16x8*)&As[(wr + m*16 + fr) * GLDK + kg];
    #pragma unroll
    for (int n = 0; n < 4; ++n) wf[n] = *(const bf16x8*)&Ws[(wc + n*16 + fr) * GLDK + kg];
    #pragma unroll
    for (int m = 0; m < 4; ++m)
      #pragma unroll
      for (int n = 0; n < 4; ++n)
        acc[m][n] = __builtin_amdgcn_mfma_f32_16x16x32_bf16(af[m], wf[n], acc[m][n], 0, 0, 0);
  }
  #pragma unroll
  for (int n = 0; n < 4; ++n) {
    const int col = bn + wc + n*16 + fr;
    const float bv = bias[col];
    #pragma unroll
    for (int m = 0; m < 4; ++m)
      #pragma unroll
      for (int r = 0; r < 4; ++r) {
        const int row = bm + wr + m*16 + rg + r;
        const float v = acc[m][n][r] + bv;
        if (OUT_BF16) ((ushort*)Cout)[(size_t)row * N + col] = f2bf(v);
        else          ((float*)Cout)[(size_t)row * N + col]  = v;
      }
  }
}

// ---------------- head-0 scores via MFMA: S = mask(relu(q0 k0^T /8)) -------
__global__ __launch_bounds__(256) void s_scores_mfma(
    const ushort* __restrict__ qkvb, float* __restrict__ SF)
{
  const int jc = blockIdx.x, it = blockIdx.y, b = blockIdx.z;
  if (jc * 8 > it) return;
  __shared__ ushort Qs[64 * SPAD], Ks[64 * SPAD];
  const int tid = threadIdx.x, lane = tid & 63, wave = tid >> 6;
  const int i0 = it * 64;
  const int fr = lane & 15, kg = (lane >> 4) * 8, rg = (lane >> 4) * 4;
  const int srow = tid >> 2, sd = (tid & 3) * 16;
  {
    const ushort* g = qkvb + (size_t)(b*TT + i0 + srow) * N3 + sd;
    bf16x8 v0 = *(const bf16x8*)g, v1 = *(const bf16x8*)(g + 8);
    *(bf16x8*)&Qs[srow*SPAD + sd]     = v0;
    *(bf16x8*)&Qs[srow*SPAD + sd + 8] = v1;
  }
  const int jt1 = min(jc*8 + 7, it);
  for (int jt = jc*8; jt <= jt1; ++jt) {
    const int j0 = jt * 64;
    __syncthreads();
    {
      const ushort* g = qkvb + (size_t)(b*TT + j0 + srow) * N3 + CC + sd;
      bf16x8 v0 = *(const bf16x8*)g, v1 = *(const bf16x8*)(g + 8);
      *(bf16x8*)&Ks[srow*SPAD + sd]     = v0;
      *(bf16x8*)&Ks[srow*SPAD + sd + 8] = v1;
    }
    __syncthreads();
    bf16x8 qf[2];
    #pragma unroll
    for (int kc = 0; kc < 2; ++kc) qf[kc] = *(const bf16x8*)&Qs[(wave*16 + fr)*SPAD + kc*32 + kg];
    #pragma unroll
    for (int n = 0; n < 4; ++n) {
      f32x4 s = (f32x4){0.f, 0.f, 0.f, 0.f};
      #pragma unroll
      for (int kc = 0; kc < 2; ++kc) {
        bf16x8 kf = *(const bf16x8*)&Ks[(n*16 + fr)*SPAD + kc*32 + kg];
        s = __builtin_amdgcn_mfma_f32_16x16x32_bf16(qf[kc], kf, s, 0, 0, 0);
      }
      const int cg = j0 + n*16 + fr;
      #pragma unroll
      for (int r = 0; r < 4; ++r) {
        const int rgg = i0 + wave*16 + rg + r;
        float v = s[r] * 0.125f;
        v = (cg < rgg && cg != 0) ? fmaxf(v, 0.f) : 0.f;
        SF[((size_t)b*TT + rgg)*TT + cg] = v;
      }
    }
  }
}

// ---------------- FF = exclusive column-prefix of S (3-phase scan) ---------
__global__ __launch_bounds__(256) void ff_pass1(const float* __restrict__ SF,
                                                float* __restrict__ part)
{
  const int jg = blockIdx.x & 7, ch = (blockIdx.x >> 3) & 15, b = blockIdx.x >> 7;
  const int j = jg*256 + threadIdx.x;
  const float* p = SF + ((size_t)b*TT + ch*128)*TT + j;
  float s = 0.f;
  for (int i = 0; i < 128; ++i) s += p[(size_t)i*TT];
  part[(b*16 + ch)*TT + j] = s;
}

__global__ __launch_bounds__(256) void ff_pass2(float* __restrict__ SF,
                                                const float* __restrict__ part)
{
  const int jg = blockIdx.x & 7, ch = (blockIdx.x >> 3) & 15, b = blockIdx.x >> 7;
  const int j = jg*256 + threadIdx.x;
  float acc = 0.f;
  for (int c = 0; c < ch; ++c) acc += part[(b*16 + c)*TT + j];
  float* p = SF + ((size_t)b*TT + ch*128)*TT + j;
  for (int i = 0; i < 128; ++i) {
    const float v = p[(size_t)i*TT];
    p[(size_t)i*TT] = acc;
    acc += v;
  }
}

// ---------------- flash attention, split-K partials --------------------------
// grid (chunk=4, bx=16, bh=32); block 4 waves x 32 q-rows; chunk = 512 keys.
// Partial (unnormalized) O -> Opart (bf16), running m/l -> ml (f32).
__global__ __launch_bounds__(256) void flash_attn5(
    const ushort* __restrict__ qkvb, const float* __restrict__ FF,
    ushort* __restrict__ Opart, float* __restrict__ ml)
{
  const int chunk = blockIdx.x, bx = blockIdx.y;
  const int nch = (bx + 4) >> 2;             // ceil((bx+1)/4)
  if (chunk >= nch) return;
  const int b = blockIdx.z >> 4, h = blockIdx.z & 15;
  const int tid = threadIdx.x, lane = tid & 63, wv = tid >> 6;
  const int hi = lane >> 5, lq = lane & 31;
  const int i0w = bx*128 + wv*32;            // wave's first q-row
  const int qg  = i0w + lq;                  // lane's q-row (global)
  __shared__ __align__(16) ushort Vt[64][72];

  // Q B-fragments: Q[qg][dc*16 + hi*8 + e]
  bf16x8 qf[4];
  const ushort* qrow = qkvb + (size_t)(b*TT + qg)*N3 + h*HD + hi*8;
  #pragma unroll
  for (int dc = 0; dc < 4; ++dc) qf[dc] = *(const bf16x8*)(qrow + dc*16);

  f32x16 o0, o1;
  #pragma unroll
  for (int r = 0; r < 16; ++r) { o0[r] = 0.f; o1[r] = 0.f; }
  float m_run = -INFINITY, l_run = 0.f;

  const int jt0 = chunk * 8;
  const int ntb = min(8, (bx + 1)*2 - jt0);  // tiles in this chunk
  const int vrow = tid & 63, vd = (tid >> 6) * 16;
  const ushort* gv0 = qkvb + (size_t)(b*TT + vrow)*N3 + 2*CC + h*HD + vd;
  {
    const ushort* gv = gv0 + (size_t)jt0*64*N3;
    bf16x8 u0 = *(const bf16x8*)gv, u1 = *(const bf16x8*)(gv + 8);

    for (int t = 0; t < ntb; ++t) {
      __syncthreads();
      #pragma unroll
      for (int e = 0; e < 8; ++e) {          // transpose write, conflict-free
        Vt[vd + e][vrow]     = (ushort)u0[e];
        Vt[vd + 8 + e][vrow] = (ushort)u1[e];
      }
      __syncthreads();
      if (t + 1 < ntb) {                     // prefetch next V tile
        const ushort* gvn = gv0 + (size_t)(jt0 + t + 1)*64*N3;
        u0 = *(const bf16x8*)gvn; u1 = *(const bf16x8*)(gvn + 8);
      }
      const int j0t = (jt0 + t)*64;
      if (j0t > i0w + 31) continue;          // wave-uniform skip

      #pragma unroll
      for (int jsub = 0; jsub < 2; ++jsub) {
        const int j0s = j0t + jsub*32;
        if (j0s > i0w + 31) continue;        // wave-uniform

        // QK^T swapped: st[j, q], K A-frags direct from global
        f32x16 st;
        #pragma unroll
        for (int r = 0; r < 16; ++r) st[r] = 0.f;
        const ushort* kr = qkvb + (size_t)(b*TT + j0s + lq)*N3 + CC + h*HD + hi*8;
        #pragma unroll
        for (int dc = 0; dc < 4; ++dc) {
          bf16x8 kf = *(const bf16x8*)(kr + dc*16);
          st = __builtin_amdgcn_mfma_f32_32x32x16_bf16(kf, qf[dc], st, 0, 0, 0);
        }
        // FF bias: 4x float4 per lane (j = j0s + 8g + 4hi + m)
        float ffv[16];
        const float* ffp = FF + (size_t)(b*TT + qg)*TT + j0s + hi*4;
        #pragma unroll
        for (int g = 0; g < 4; ++g) {
          float4 tq = *(const float4*)(ffp + 8*g);
          ffv[4*g]=tq.x; ffv[4*g+1]=tq.y; ffv[4*g+2]=tq.z; ffv[4*g+3]=tq.w;
        }
        float lg[16];
        float pmax = -INFINITY;
        const bool need_mask = (j0s + 31 > i0w);
        #pragma unroll
        for (int r = 0; r < 16; ++r) {
          float v = st[r]*0.125f - ffv[r];
          if (need_mask) {
            const int j = j0s + (r&3) + 8*(r>>2) + 4*hi;
            v = (j <= qg) ? v : -INFINITY;
          }
          lg[r] = v;
          pmax = fmaxf(pmax, v);
        }
        pmax = fmaxf(pmax, __shfl_xor(pmax, 32));
        if (!__all(pmax <= m_run)) {         // T13 defer-max
          const float mn = fmaxf(m_run, pmax);
          const float sc = __expf(m_run - mn);
          m_run = mn;
          l_run *= sc;
          #pragma unroll
          for (int r = 0; r < 16; ++r) {
            const float s0 = __shfl(sc, (r&3) + 8*(r>>2) + 4*hi);
            o0[r] *= s0; o1[r] *= s0;
          }
        }
        float rs = 0.f;
        #pragma unroll
        for (int r = 0; r < 16; ++r) {
          const float pe = __expf(lg[r] - m_run);
          lg[r] = pe;
          rs += pe;
        }
        rs += __shfl_xor(rs, 32);
        l_run += rs;
        uint32_t P8[8], Q8[8];
        #pragma unroll
        for (int g = 0; g < 4; ++g) {
          P8[2*g]   = cvt_pk_bf16(lg[4*g],   lg[4*g+1]);
          P8[2*g+1] = cvt_pk_bf16(lg[4*g+2], lg[4*g+3]);
        }
        #pragma unroll
        for (int k = 0; k < 8; ++k) Q8[k] = (uint32_t)__shfl_xor((int)P8[k], 32);
        #pragma unroll
        for (int mm = 0; mm < 2; ++mm) {
          pack4_t pk;
          pk.u[0] = hi ? Q8[4*mm+2] : P8[4*mm];
          pk.u[1] = hi ? Q8[4*mm+3] : P8[4*mm+1];
          pk.u[2] = hi ? P8[4*mm+2] : Q8[4*mm];
          pk.u[3] = hi ? P8[4*mm+3] : Q8[4*mm+1];
          const bf16x8 pa = pk.v;
          const bf16x8 v0 = *(const bf16x8*)&Vt[lq]     [jsub*32 + mm*16 + hi*8];
          const bf16x8 v1 = *(const bf16x8*)&Vt[32 + lq][jsub*32 + mm*16 + hi*8];
          o0 = __builtin_amdgcn_mfma_f32_32x32x16_bf16(pa, v0, o0, 0, 0, 0);
          o1 = __builtin_amdgcn_mfma_f32_32x32x16_bf16(pa, v1, o1, 0, 0, 0);
        }
      }
    }
  }
  // epilogue: write partials (unnormalized)
  const int g2 = bx >> 2, r2 = bx & 3;
  const int prefix = 2*g2*(g2+1) + r2*(g2+1);
  const int slot = (b*NH + h)*NSLOT + prefix + chunk;
  if (hi == 0) {
    const int rowin = wv*32 + lq;
    ml[(slot*128 + rowin)*2]     = m_run;
    ml[(slot*128 + rowin)*2 + 1] = l_run;
  }
  #pragma unroll
  for (int r = 0; r < 16; ++r) {
    const int qm = (r&3) + 8*(r>>2) + 4*hi;
    const size_t base = ((size_t)slot*128 + wv*32 + qm)*64;
    Opart[base + lq]      = f2bf(o0[r]);
    Opart[base + 32 + lq] = f2bf(o1[r]);
  }
}

// ---------------- combine split-K partials -> Yb (bf16) --------------------
__global__ __launch_bounds__(256) void attn_combine(
    const ushort* __restrict__ Opart, const float* __restrict__ ml,
    ushort* __restrict__ Yb)
{
  const int wv = threadIdx.x >> 6, lane = threadIdx.x & 63;
  const int flat = blockIdx.x*4 + wv;        // (b*TT + row)*NH + h
  const int h = flat & 15;
  const int t = flat >> 4;                   // b*TT + row
  const int row = t & (TT-1), b = t >> 11;
  const int bx = row >> 7;
  const int nch = (bx + 4) >> 2;
  const int g2 = bx >> 2, r2 = bx & 3;
  const int slot0 = (b*NH + h)*NSLOT + 2*g2*(g2+1) + r2*(g2+1);
  const int rowin = row & 127;

  float M = -INFINITY;
  for (int i = 0; i < nch; ++i)
    M = fmaxf(M, ml[((slot0 + i)*128 + rowin)*2]);
  float L = 0.f, acc = 0.f;
  for (int i = 0; i < nch; ++i) {
    const float mi = ml[((slot0 + i)*128 + rowin)*2];
    const float li = ml[((slot0 + i)*128 + rowin)*2 + 1];
    const float w = __expf(mi - M);
    L += li * w;
    acc += bf2f(Opart[((size_t)(slot0 + i)*128 + rowin)*64 + lane]) * w;
  }
  Yb[(size_t)t*CC + h*HD + lane] = f2bf(acc / L);
}

// ---------------------------------------------------------------------------
extern "C" void kernel_launch(void* const* d_in, const int* in_sizes, int n_in,
                              void* d_out, int out_size, void* d_ws, size_t ws_size,
                              hipStream_t stream) {
  const float* x      = (const float*)d_in[0];
  const float* w_attn = (const float*)d_in[1];
  const float* b_attn = (const float*)d_in[2];
  const float* w_proj = (const float*)d_in[3];
  const float* b_proj = (const float*)d_in[4];
  float* out = (float*)d_out;

  ushort* xb   = (ushort*)d_ws;                         // B*T*C bf16
  ushort* wab  = xb   + (size_t)BB*TT*CC;               // 3C*C bf16
  ushort* wpb  = wab  + (size_t)N3*CC;                  // C*C bf16
  ushort* qkvb = wpb  + (size_t)CC*CC;                  // B*T*3C bf16
  ushort* Yb   = qkvb + (size_t)BB*TT*N3;               // B*T*C bf16
  float*  SF   = (float*)(Yb + (size_t)BB*TT*CC);       // B*T*T f32 (S then FF)
  float*  part = SF + (size_t)BB*TT*TT;                 // B*16*T f32
  ushort* Opart= (ushort*)(part + (size_t)BB*16*TT);    // 1280*128*64 bf16 (21MB)
  float*  ml   = (float*)(Opart + (size_t)BB*NH*NSLOT*128*64); // 1280*128*2 f32

  cast_bf16_k<<<(BB*TT*CC/4 + 255)/256, 256, 0, stream>>>(x, xb, BB*TT*CC);
  cast_bf16_k<<<(N3*CC/4 + 255)/256, 256, 0, stream>>>(w_attn, wab, N3*CC);
  cast_bf16_k<<<(CC*CC/4 + 255)/256, 256, 0, stream>>>(w_proj, wpb, CC*CC);

  gemm_mfma<true><<<dim3(N3/128, (BB*TT)/128), 256, 0, stream>>>(
      xb, wab, b_attn, (void*)qkvb, BB*TT, N3, CC);

  hipMemsetAsync(SF, 0, (size_t)BB*TT*TT*sizeof(float), stream);
  s_scores_mfma<<<dim3(4, TT/64, BB), 256, 0, stream>>>(qkvb, SF);

  ff_pass1<<<256, 256, 0, stream>>>(SF, part);
  ff_pass2<<<256, 256, 0, stream>>>(SF, part);

  flash_attn5<<<dim3(4, 16, BB*NH), 256, 0, stream>>>(qkvb, SF, Opart, ml);
  attn_combine<<<(BB*TT*NH)/4, 256, 0, stream>>>(Opart, ml, Yb);

  gemm_mfma<false><<<dim3(CC/128, (BB*TT)/128), 256, 0, stream>>>(
      Yb, wpb, b_proj, (void*)out, BB*TT, CC, CC);
}

// Round 8
// 180.546 us; speedup vs baseline: 1.5399x; 1.5399x over previous
//
#include <hip/hip_runtime.h>
#include <hip/hip_fp16.h>
#include <stdint.h>
#include <math.h>

#define BB 2
#define TT 2048
#define CC 1024
#define NH 16
#define HD 64
#define N3 (3*CC)
#define NT (TT/64)
#define SPAD 74         // LDS row stride for 16x16-path kernels
#define FFTHR 50.0f     // skip tiles with min FF > 50: weight <= e^-45

typedef __attribute__((ext_vector_type(8)))  short bf16x8;
typedef __attribute__((ext_vector_type(4)))  float f32x4;
typedef __attribute__((ext_vector_type(16))) float f32x16;

__device__ inline ushort f2bf(float f) {
  uint32_t u = __float_as_uint(f);
  u += 0x7fff + ((u >> 16) & 1);          // RNE
  return (ushort)(u >> 16);
}
__device__ inline uint32_t cvt_pk_bf16(float lo, float hi_) {
  uint32_t r;
  asm("v_cvt_pk_bf16_f32 %0, %1, %2" : "=v"(r) : "v"(lo), "v"(hi_));
  return r;
}

typedef union { uint32_t u[4]; bf16x8 v; } pack4_t;

// ---------------- cast f32 -> bf16, vectorized ----------------
__global__ __launch_bounds__(256) void cast_bf16_k(const float* __restrict__ in,
                                                   ushort* __restrict__ out, int n)
{
  int i = (blockIdx.x * 256 + threadIdx.x) * 4;
  if (i + 3 < n) {
    float4 v = *(const float4*)(in + i);
    ushort4 o;
    o.x = f2bf(v.x); o.y = f2bf(v.y); o.z = f2bf(v.z); o.w = f2bf(v.w);
    *(ushort4*)(out + i) = o;
  }
}

// ---------------- bf16 MFMA GEMM: C[M,N] = A[M,K] @ W[N,K]^T + bias --------
#define GLDK 40

template<bool OUT_BF16>
__global__ __launch_bounds__(256) void gemm_mfma(
    const ushort* __restrict__ A, const ushort* __restrict__ W,
    const float* __restrict__ bias, void* __restrict__ Cout,
    int M, int N, int K)
{
  __shared__ ushort As[128 * GLDK];
  __shared__ ushort Ws[128 * GLDK];
  const int tid = threadIdx.x;
  const int lane = tid & 63, wave = tid >> 6;
  const int wr = (wave >> 1) * 64, wc = (wave & 1) * 64;
  const int bm = blockIdx.y * 128, bn = blockIdx.x * 128;
  const int fr = lane & 15, kg = (lane >> 4) * 8, rg = (lane >> 4) * 4;
  const int srow = tid >> 1, skb = (tid & 1) * 16;
  f32x4 acc[4][4];
  #pragma unroll
  for (int i=0;i<4;++i)
    #pragma unroll
    for (int j=0;j<4;++j) acc[i][j]=(f32x4){0.f,0.f,0.f,0.f};

  const ushort* ag = A + (size_t)(bm + srow) * K + skb;
  const ushort* wg = W + (size_t)(bn + srow) * K + skb;
  for (int k0 = 0; k0 < K; k0 += 32) {
    bf16x8 a0 = *(const bf16x8*)(ag + k0);
    bf16x8 a1 = *(const bf16x8*)(ag + k0 + 8);
    bf16x8 w0 = *(const bf16x8*)(wg + k0);
    bf16x8 w1 = *(const bf16x8*)(wg + k0 + 8);
    __syncthreads();
    *(bf16x8*)&As[srow * GLDK + skb]     = a0;
    *(bf16x8*)&As[srow * GLDK + skb + 8] = a1;
    *(bf16x8*)&Ws[srow * GLDK + skb]     = w0;
    *(bf16x8*)&Ws[srow * GLDK + skb + 8] = w1;
    __syncthreads();
    bf16x8 af[4], wf[4];
    #pragma unroll
    for (int m = 0; m < 4; ++m) af[m] = *(const bf16x8*)&As[(wr + m*16 + fr) * GLDK + kg];
    #pragma unroll
    for (int n = 0; n < 4; ++n) wf[n] = *(const bf16x8*)&Ws[(wc + n*16 + fr) * GLDK + kg];
    #pragma unroll
    for (int m = 0; m < 4; ++m)
      #pragma unroll
      for (int n = 0; n < 4; ++n)
        acc[m][n] = __builtin_amdgcn_mfma_f32_16x16x32_bf16(af[m], wf[n], acc[m][n], 0, 0, 0);
  }
  #pragma unroll
  for (int n = 0; n < 4; ++n) {
    const int col = bn + wc + n*16 + fr;
    const float bv = bias[col];
    #pragma unroll
    for (int m = 0; m < 4; ++m)
      #pragma unroll
      for (int r = 0; r < 4; ++r) {
        const int row = bm + wr + m*16 + rg + r;
        const float v = acc[m][n][r] + bv;
        if (OUT_BF16) ((ushort*)Cout)[(size_t)row * N + col] = f2bf(v);
        else          ((float*)Cout)[(size_t)row * N + col]  = v;
      }
  }
}

// ---------------- head-0 scores via MFMA: S = mask(relu(q0 k0^T /8)) -------
__global__ __launch_bounds__(256) void s_scores_mfma(
    const ushort* __restrict__ qkvb, float* __restrict__ SF)
{
  const int jc = blockIdx.x, it = blockIdx.y, b = blockIdx.z;
  if (jc * 8 > it) return;
  __shared__ ushort Qs[64 * SPAD], Ks[64 * SPAD];
  const int tid = threadIdx.x, lane = tid & 63, wave = tid >> 6;
  const int i0 = it * 64;
  const int fr = lane & 15, kg = (lane >> 4) * 8, rg = (lane >> 4) * 4;
  const int srow = tid >> 2, sd = (tid & 3) * 16;
  {
    const ushort* g = qkvb + (size_t)(b*TT + i0 + srow) * N3 + sd;
    bf16x8 v0 = *(const bf16x8*)g, v1 = *(const bf16x8*)(g + 8);
    *(bf16x8*)&Qs[srow*SPAD + sd]     = v0;
    *(bf16x8*)&Qs[srow*SPAD + sd + 8] = v1;
  }
  const int jt1 = min(jc*8 + 7, it);
  for (int jt = jc*8; jt <= jt1; ++jt) {
    const int j0 = jt * 64;
    __syncthreads();
    {
      const ushort* g = qkvb + (size_t)(b*TT + j0 + srow) * N3 + CC + sd;
      bf16x8 v0 = *(const bf16x8*)g, v1 = *(const bf16x8*)(g + 8);
      *(bf16x8*)&Ks[srow*SPAD + sd]     = v0;
      *(bf16x8*)&Ks[srow*SPAD + sd + 8] = v1;
    }
    __syncthreads();
    bf16x8 qf[2];
    #pragma unroll
    for (int kc = 0; kc < 2; ++kc) qf[kc] = *(const bf16x8*)&Qs[(wave*16 + fr)*SPAD + kc*32 + kg];
    #pragma unroll
    for (int n = 0; n < 4; ++n) {
      f32x4 s = (f32x4){0.f, 0.f, 0.f, 0.f};
      #pragma unroll
      for (int kc = 0; kc < 2; ++kc) {
        bf16x8 kf = *(const bf16x8*)&Ks[(n*16 + fr)*SPAD + kc*32 + kg];
        s = __builtin_amdgcn_mfma_f32_16x16x32_bf16(qf[kc], kf, s, 0, 0, 0);
      }
      const int cg = j0 + n*16 + fr;
      #pragma unroll
      for (int r = 0; r < 4; ++r) {
        const int rgg = i0 + wave*16 + rg + r;
        float v = s[r] * 0.125f;
        v = (cg < rgg && cg != 0) ? fmaxf(v, 0.f) : 0.f;
        SF[((size_t)b*TT + rgg)*TT + cg] = v;
      }
    }
  }
}

// ---------------- FF scan: pass1 partials, pass2 -> transposed fp16 --------
__global__ __launch_bounds__(256) void ff_pass1(const float* __restrict__ SF,
                                                float* __restrict__ part)
{
  const int jg = blockIdx.x & 7, ch = (blockIdx.x >> 3) & 15, b = blockIdx.x >> 7;
  const int j = jg*256 + threadIdx.x;
  const float* p = SF + ((size_t)b*TT + ch*128)*TT + j;
  float s = 0.f;
  for (int i = 0; i < 128; ++i) s += p[(size_t)i*TT];
  part[(b*16 + ch)*TT + j] = s;
}

// exclusive prefix over i (f32 accum), stored transposed fp16: FFT[b][j][i]
__global__ __launch_bounds__(256) void ff_pass2t(const float* __restrict__ SF,
                                                 const float* __restrict__ part,
                                                 __half* __restrict__ FFT)
{
  const int jg = blockIdx.x & 7, ch = (blockIdx.x >> 3) & 15, b = blockIdx.x >> 7;
  const int j = jg*256 + threadIdx.x;
  float acc = 0.f;
  for (int c = 0; c < ch; ++c) acc += part[(b*16 + c)*TT + j];
  const float* p = SF + ((size_t)b*TT + ch*128)*TT + j;
  __half* q = FFT + (size_t)b*TT*TT + (size_t)j*TT + ch*128;
  for (int i = 0; i < 128; ++i) {
    q[i] = __float2half_rn(acc);
    acc += p[(size_t)i*TT];
  }
}

// ---------------- per-tile FF minimum: minFF[b][jt32][ib32] ----------------
// FF is nondecreasing in i, so tile min = min over j of FF[ib*32][j-tile].
__global__ __launch_bounds__(256) void minff_k(const __half* __restrict__ FFT,
                                               float* __restrict__ minFF)
{
  const int b = blockIdx.x >> 6, ib = blockIdx.x & 63;
  const int tid = threadIdx.x;
  const __half* base = FFT + (size_t)b*TT*TT + (size_t)(tid*8)*TT + ib*32;
  float mn = INFINITY;
  #pragma unroll
  for (int e = 0; e < 8; ++e)
    mn = fminf(mn, __half2float(base[(size_t)e*TT]));
  mn = fminf(mn, __shfl_xor(mn, 1));
  mn = fminf(mn, __shfl_xor(mn, 2));
  if ((tid & 3) == 0)
    minFF[(b*64 + (tid >> 2))*64 + ib] = mn;
}

// ---------------- flash attention: swapped QK^T, FF-skip, FFT reads --------
// grid (bx=16, bh=32); block 4 waves x 32 q-rows = 128 rows.
__global__ __launch_bounds__(256) void flash_attn6(
    const ushort* __restrict__ qkvb, const __half* __restrict__ FFT,
    const float* __restrict__ minFF, ushort* __restrict__ Yb)
{
  const int bx = blockIdx.x;
  const int b = blockIdx.y >> 4, h = blockIdx.y & 15;
  const int tid = threadIdx.x, lane = tid & 63, wv = tid >> 6;
  const int hi = lane >> 5, lq = lane & 31;
  const int i0w = bx*128 + wv*32;            // wave's first q-row
  const int qg  = i0w + lq;                  // lane's q-row
  __shared__ __align__(16) ushort Vt[64][72];
  __shared__ short keep_list[32];
  __shared__ int s_nk;

  const int jtmax = 2*bx + 1;
  const int ibblk = bx*4;                    // i-block (32) index of block top
  // build kept 64-key-tile list (block-uniform skip via block-top FF min)
  if (tid < 64) {
    bool kp = false;
    if (tid <= jtmax) {
      const float m0 = minFF[(b*64 + 2*tid)*64 + ibblk];
      const float m1 = minFF[(b*64 + 2*tid + 1)*64 + ibblk];
      kp = fminf(m0, m1) <= FFTHR;
    }
    const unsigned long long mask = __ballot(kp);
    if (tid == 0) {
      int n = 0;
      unsigned long long m = mask;
      while (m) { keep_list[n++] = (short)__builtin_ctzll(m); m &= m - 1; }
      s_nk = n;
    }
  }

  // Q B-fragments: Q[qg][dc*16 + hi*8 + e]
  bf16x8 qf[4];
  const ushort* qrow = qkvb + (size_t)(b*TT + qg)*N3 + h*HD + hi*8;
  #pragma unroll
  for (int dc = 0; dc < 4; ++dc) qf[dc] = *(const bf16x8*)(qrow + dc*16);

  f32x16 o0, o1;
  #pragma unroll
  for (int r = 0; r < 16; ++r) { o0[r] = 0.f; o1[r] = 0.f; }
  float m_run = -INFINITY, l_run = 0.f;

  const int vrow = tid & 63, vd = (tid >> 6) * 16;
  const ushort* gv0 = qkvb + (size_t)(b*TT + vrow)*N3 + 2*CC + h*HD + vd;

  __syncthreads();                           // keep_list ready
  const int nk = s_nk;
  bf16x8 u0, u1;
  {
    const size_t off = (size_t)keep_list[0]*64*N3;
    u0 = *(const bf16x8*)(gv0 + off);
    u1 = *(const bf16x8*)(gv0 + off + 8);
  }

  for (int idx = 0; idx < nk; ++idx) {
    const int jt = keep_list[idx];
    const int j0t = jt*64;
    // issue this tile's K loads early (hidden under barriers + Vt write)
    bf16x8 kt[2][4];
    const bool wave_live = (j0t <= i0w + 31);   // wave-uniform
    if (wave_live) {
      #pragma unroll
      for (int js = 0; js < 2; ++js) {
        const ushort* kr = qkvb + (size_t)(b*TT + j0t + js*32 + lq)*N3 + CC + h*HD + hi*8;
        #pragma unroll
        for (int dc = 0; dc < 4; ++dc) kt[js][dc] = *(const bf16x8*)(kr + dc*16);
      }
    }
    __syncthreads();                         // prev tile's LDS reads done
    #pragma unroll
    for (int e = 0; e < 8; ++e) {            // conflict-free transpose write
      Vt[vd + e][vrow]     = (ushort)u0[e];
      Vt[vd + 8 + e][vrow] = (ushort)u1[e];
    }
    __syncthreads();
    if (idx + 1 < nk) {                      // prefetch next kept V tile
      const size_t off = (size_t)keep_list[idx+1]*64*N3;
      u0 = *(const bf16x8*)(gv0 + off);
      u1 = *(const bf16x8*)(gv0 + off + 8);
    }
    if (!wave_live) continue;

    #pragma unroll
    for (int jsub = 0; jsub < 2; ++jsub) {
      const int j0s = j0t + jsub*32;
      if (j0s > i0w + 31) continue;          // wave-uniform causal skip
      // wave-level fine skip (this wave's own i-block)
      const float mw = minFF[(b*64 + (j0s >> 5))*64 + (i0w >> 5)];
      if (mw > FFTHR) continue;

      // FF bias from transposed fp16: coalesced across lanes
      float ffv[16];
      {
        const __half* fft = FFT + (size_t)b*TT*TT + (size_t)j0s*TT + qg;
        #pragma unroll
        for (int r = 0; r < 16; ++r) {
          const int joff = (r&3) + 8*(r>>2) + 4*hi;
          ffv[r] = __half2float(fft[(size_t)joff*TT]);
        }
      }
      // QK^T swapped: st[j, q]
      f32x16 st;
      #pragma unroll
      for (int r = 0; r < 16; ++r) st[r] = 0.f;
      #pragma unroll
      for (int dc = 0; dc < 4; ++dc)
        st = __builtin_amdgcn_mfma_f32_32x32x16_bf16(kt[jsub][dc], qf[dc], st, 0, 0, 0);

      float lg[16];
      float pmax = -INFINITY;
      const bool need_mask = (j0s + 31 > i0w);
      #pragma unroll
      for (int r = 0; r < 16; ++r) {
        float v = st[r]*0.125f - ffv[r];
        if (need_mask) {
          const int j = j0s + (r&3) + 8*(r>>2) + 4*hi;
          v = (j <= qg) ? v : -INFINITY;
        }
        lg[r] = v;
        pmax = fmaxf(pmax, v);
      }
      pmax = fmaxf(pmax, __shfl_xor(pmax, 32));
      if (!__all(pmax <= m_run)) {           // T13 defer-max
        const float mn = fmaxf(m_run, pmax);
        const float sc = __expf(m_run - mn);
        m_run = mn;
        l_run *= sc;
        #pragma unroll
        for (int r = 0; r < 16; ++r) {
          const float s0 = __shfl(sc, (r&3) + 8*(r>>2) + 4*hi);
          o0[r] *= s0; o1[r] *= s0;
        }
      }
      float rs = 0.f;
      #pragma unroll
      for (int r = 0; r < 16; ++r) {
        const float pe = __expf(lg[r] - m_run);
        lg[r] = pe;
        rs += pe;
      }
      rs += __shfl_xor(rs, 32);
      l_run += rs;
      // pack P into A-fragments
      uint32_t P8[8], Q8[8];
      #pragma unroll
      for (int g = 0; g < 4; ++g) {
        P8[2*g]   = cvt_pk_bf16(lg[4*g],   lg[4*g+1]);
        P8[2*g+1] = cvt_pk_bf16(lg[4*g+2], lg[4*g+3]);
      }
      #pragma unroll
      for (int k = 0; k < 8; ++k) Q8[k] = (uint32_t)__shfl_xor((int)P8[k], 32);
      #pragma unroll
      for (int mm = 0; mm < 2; ++mm) {
        pack4_t pk;
        pk.u[0] = hi ? Q8[4*mm+2] : P8[4*mm];
        pk.u[1] = hi ? Q8[4*mm+3] : P8[4*mm+1];
        pk.u[2] = hi ? P8[4*mm+2] : Q8[4*mm];
        pk.u[3] = hi ? P8[4*mm+3] : Q8[4*mm+1];
        const bf16x8 pa = pk.v;
        const bf16x8 v0 = *(const bf16x8*)&Vt[lq]     [jsub*32 + mm*16 + hi*8];
        const bf16x8 v1 = *(const bf16x8*)&Vt[32 + lq][jsub*32 + mm*16 + hi*8];
        o0 = __builtin_amdgcn_mfma_f32_32x32x16_bf16(pa, v0, o0, 0, 0, 0);
        o1 = __builtin_amdgcn_mfma_f32_32x32x16_bf16(pa, v1, o1, 0, 0, 0);
      }
    }
  }
  // epilogue
  const float invl = 1.0f / l_run;
  #pragma unroll
  for (int r = 0; r < 16; ++r) {
    const int qm = (r&3) + 8*(r>>2) + 4*hi;
    const float il = __shfl(invl, qm);
    const size_t row = (size_t)(b*TT + i0w + qm)*CC + h*HD;
    Yb[row + lq]      = f2bf(o0[r] * il);
    Yb[row + 32 + lq] = f2bf(o1[r] * il);
  }
}

// ---------------------------------------------------------------------------
extern "C" void kernel_launch(void* const* d_in, const int* in_sizes, int n_in,
                              void* d_out, int out_size, void* d_ws, size_t ws_size,
                              hipStream_t stream) {
  const float* x      = (const float*)d_in[0];
  const float* w_attn = (const float*)d_in[1];
  const float* b_attn = (const float*)d_in[2];
  const float* w_proj = (const float*)d_in[3];
  const float* b_proj = (const float*)d_in[4];
  float* out = (float*)d_out;

  ushort* xb   = (ushort*)d_ws;                         // B*T*C bf16
  ushort* wab  = xb   + (size_t)BB*TT*CC;               // 3C*C bf16
  ushort* wpb  = wab  + (size_t)N3*CC;                  // C*C bf16
  ushort* qkvb = wpb  + (size_t)CC*CC;                  // B*T*3C bf16
  ushort* Yb   = qkvb + (size_t)BB*TT*N3;               // B*T*C bf16
  float*  SF   = (float*)(Yb + (size_t)BB*TT*CC);       // B*T*T f32 (S scores)
  float*  part = SF + (size_t)BB*TT*TT;                 // B*16*T f32
  __half* FFT  = (__half*)(part + (size_t)BB*16*TT);    // B*T*T fp16 transposed
  float*  minFF= (float*)(FFT + (size_t)BB*TT*TT);      // B*64*64 f32

  cast_bf16_k<<<(BB*TT*CC/4 + 255)/256, 256, 0, stream>>>(x, xb, BB*TT*CC);
  cast_bf16_k<<<(N3*CC/4 + 255)/256, 256, 0, stream>>>(w_attn, wab, N3*CC);
  cast_bf16_k<<<(CC*CC/4 + 255)/256, 256, 0, stream>>>(w_proj, wpb, CC*CC);

  gemm_mfma<true><<<dim3(N3/128, (BB*TT)/128), 256, 0, stream>>>(
      xb, wab, b_attn, (void*)qkvb, BB*TT, N3, CC);

  hipMemsetAsync(SF, 0, (size_t)BB*TT*TT*sizeof(float), stream);
  s_scores_mfma<<<dim3(4, TT/64, BB), 256, 0, stream>>>(qkvb, SF);

  ff_pass1<<<256, 256, 0, stream>>>(SF, part);
  ff_pass2t<<<256, 256, 0, stream>>>(SF, part, FFT);
  minff_k<<<BB*64, 256, 0, stream>>>(FFT, minFF);

  flash_attn6<<<dim3(TT/128, BB*NH), 256, 0, stream>>>(qkvb, FFT, minFF, Yb);

  gemm_mfma<false><<<dim3(CC/128, (BB*TT)/128), 256, 0, stream>>>(
      Yb, wpb, b_proj, (void*)out, BB*TT, CC, CC);
}

// Round 9
// 177.297 us; speedup vs baseline: 1.5681x; 1.0183x over previous
//
#include <hip/hip_runtime.h>
#include <hip/hip_fp16.h>
#include <stdint.h>
#include <math.h>

#define BB 2
#define TT 2048
#define CC 1024
#define NH 16
#define HD 64
#define N3 (3*CC)
#define NT (TT/64)
#define SPAD 74         // LDS row stride for 16x16-path kernels
#define FFTHR 50.0f     // skip tiles with min FF > 50: weight <= e^-45

typedef __attribute__((ext_vector_type(8)))  short bf16x8;
typedef __attribute__((ext_vector_type(4)))  float f32x4;
typedef __attribute__((ext_vector_type(16))) float f32x16;

__device__ inline ushort f2bf(float f) {
  uint32_t u = __float_as_uint(f);
  u += 0x7fff + ((u >> 16) & 1);          // RNE
  return (ushort)(u >> 16);
}
__device__ inline uint32_t cvt_pk_bf16(float lo, float hi_) {
  uint32_t r;
  asm("v_cvt_pk_bf16_f32 %0, %1, %2" : "=v"(r) : "v"(lo), "v"(hi_));
  return r;
}

// direct global -> LDS staging, 16B per lane (dest = wave-uniform base + lane*16)
__device__ inline void gll16(const ushort* g, ushort* l) {
  __builtin_amdgcn_global_load_lds(
      (uint32_t __attribute__((address_space(1)))*)(g),
      (uint32_t __attribute__((address_space(3)))*)(l), 16, 0, 0);
}

typedef union { uint32_t u[4]; bf16x8 v; } pack4_t;

// ---------------- cast f32 -> bf16, vectorized ----------------
__global__ __launch_bounds__(256) void cast_bf16_k(const float* __restrict__ in,
                                                   ushort* __restrict__ out, int n)
{
  int i = (blockIdx.x * 256 + threadIdx.x) * 4;
  if (i + 3 < n) {
    float4 v = *(const float4*)(in + i);
    ushort4 o;
    o.x = f2bf(v.x); o.y = f2bf(v.y); o.z = f2bf(v.z); o.w = f2bf(v.w);
    *(ushort4*)(out + i) = o;
  }
}

// ---------------- bf16 MFMA GEMM, global_load_lds staging (m97 structure) --
// C[M,N] = A[M,K] @ W[N,K]^T + bias. 128x128 tile, BK=32, 4 waves (2x2 of 64).
template<bool OUT_BF16>
__global__ __launch_bounds__(256) void gemm_lds(
    const ushort* __restrict__ A, const ushort* __restrict__ W,
    const float* __restrict__ bias, void* __restrict__ Cout,
    int M, int N, int K)
{
  __shared__ ushort As[128 * 32];   // linear [row][k], 64B rows
  __shared__ ushort Ws[128 * 32];
  const int tid = threadIdx.x;
  const int lane = tid & 63, wave = tid >> 6;
  const int wr = (wave >> 1) * 64, wc = (wave & 1) * 64;
  const int bm = blockIdx.y * 128, bn = blockIdx.x * 128;
  const int fr = lane & 15, kg = (lane >> 4) * 8, rg = (lane >> 4) * 4;

  // staging: wave covers rows wave*32 .. wave*32+31 (2 loads of 16 rows each)
  const int srow = wave*32 + (lane >> 2);
  const int scol = (lane & 3) * 8;
  const ushort* ga0 = A + (size_t)(bm + srow) * K + scol;
  const ushort* ga1 = A + (size_t)(bm + srow + 16) * K + scol;
  const ushort* gw0 = W + (size_t)(bn + srow) * K + scol;
  const ushort* gw1 = W + (size_t)(bn + srow + 16) * K + scol;
  ushort* lA0 = &As[wave*1024];          // wave-uniform LDS bases
  ushort* lA1 = &As[wave*1024 + 512];
  ushort* lW0 = &Ws[wave*1024];
  ushort* lW1 = &Ws[wave*1024 + 512];

  f32x4 acc[4][4];
  #pragma unroll
  for (int i=0;i<4;++i)
    #pragma unroll
    for (int j=0;j<4;++j) acc[i][j]=(f32x4){0.f,0.f,0.f,0.f};

  for (int k0 = 0; k0 < K; k0 += 32) {
    __syncthreads();                     // prev frag reads done
    gll16(ga0 + k0, lA0);
    gll16(ga1 + k0, lA1);
    gll16(gw0 + k0, lW0);
    gll16(gw1 + k0, lW1);
    __syncthreads();                     // vmcnt drained: tiles staged
    bf16x8 af[4], wf[4];
    #pragma unroll
    for (int m = 0; m < 4; ++m) af[m] = *(const bf16x8*)&As[(wr + m*16 + fr)*32 + kg];
    #pragma unroll
    for (int n = 0; n < 4; ++n) wf[n] = *(const bf16x8*)&Ws[(wc + n*16 + fr)*32 + kg];
    #pragma unroll
    for (int m = 0; m < 4; ++m)
      #pragma unroll
      for (int n = 0; n < 4; ++n)
        acc[m][n] = __builtin_amdgcn_mfma_f32_16x16x32_bf16(af[m], wf[n], acc[m][n], 0, 0, 0);
  }
  #pragma unroll
  for (int n = 0; n < 4; ++n) {
    const int col = bn + wc + n*16 + fr;
    const float bv = bias[col];
    #pragma unroll
    for (int m = 0; m < 4; ++m)
      #pragma unroll
      for (int r = 0; r < 4; ++r) {
        const int row = bm + wr + m*16 + rg + r;
        const float v = acc[m][n][r] + bv;
        if (OUT_BF16) ((ushort*)Cout)[(size_t)row * N + col] = f2bf(v);
        else          ((float*)Cout)[(size_t)row * N + col]  = v;
      }
  }
}

// ---------------- head-0 scores via MFMA: S = mask(relu(q0 k0^T /8)) -------
__global__ __launch_bounds__(256) void s_scores_mfma(
    const ushort* __restrict__ qkvb, float* __restrict__ SF)
{
  const int jc = blockIdx.x, it = blockIdx.y, b = blockIdx.z;
  if (jc * 8 > it) return;
  __shared__ ushort Qs[64 * SPAD], Ks[64 * SPAD];
  const int tid = threadIdx.x, lane = tid & 63, wave = tid >> 6;
  const int i0 = it * 64;
  const int fr = lane & 15, kg = (lane >> 4) * 8, rg = (lane >> 4) * 4;
  const int srow = tid >> 2, sd = (tid & 3) * 16;
  {
    const ushort* g = qkvb + (size_t)(b*TT + i0 + srow) * N3 + sd;
    bf16x8 v0 = *(const bf16x8*)g, v1 = *(const bf16x8*)(g + 8);
    *(bf16x8*)&Qs[srow*SPAD + sd]     = v0;
    *(bf16x8*)&Qs[srow*SPAD + sd + 8] = v1;
  }
  const int jt1 = min(jc*8 + 7, it);
  for (int jt = jc*8; jt <= jt1; ++jt) {
    const int j0 = jt * 64;
    __syncthreads();
    {
      const ushort* g = qkvb + (size_t)(b*TT + j0 + srow) * N3 + CC + sd;
      bf16x8 v0 = *(const bf16x8*)g, v1 = *(const bf16x8*)(g + 8);
      *(bf16x8*)&Ks[srow*SPAD + sd]     = v0;
      *(bf16x8*)&Ks[srow*SPAD + sd + 8] = v1;
    }
    __syncthreads();
    bf16x8 qf[2];
    #pragma unroll
    for (int kc = 0; kc < 2; ++kc) qf[kc] = *(const bf16x8*)&Qs[(wave*16 + fr)*SPAD + kc*32 + kg];
    #pragma unroll
    for (int n = 0; n < 4; ++n) {
      f32x4 s = (f32x4){0.f, 0.f, 0.f, 0.f};
      #pragma unroll
      for (int kc = 0; kc < 2; ++kc) {
        bf16x8 kf = *(const bf16x8*)&Ks[(n*16 + fr)*SPAD + kc*32 + kg];
        s = __builtin_amdgcn_mfma_f32_16x16x32_bf16(qf[kc], kf, s, 0, 0, 0);
      }
      const int cg = j0 + n*16 + fr;
      #pragma unroll
      for (int r = 0; r < 4; ++r) {
        const int rgg = i0 + wave*16 + rg + r;
        float v = s[r] * 0.125f;
        v = (cg < rgg && cg != 0) ? fmaxf(v, 0.f) : 0.f;
        SF[((size_t)b*TT + rgg)*TT + cg] = v;
      }
    }
  }
}

// ---------------- FF scan: pass1 partials, pass2 -> transposed fp16 --------
__global__ __launch_bounds__(256) void ff_pass1(const float* __restrict__ SF,
                                                float* __restrict__ part)
{
  const int jg = blockIdx.x & 7, ch = (blockIdx.x >> 3) & 15, b = blockIdx.x >> 7;
  const int j = jg*256 + threadIdx.x;
  const float* p = SF + ((size_t)b*TT + ch*128)*TT + j;
  float s = 0.f;
  for (int i = 0; i < 128; ++i) s += p[(size_t)i*TT];
  part[(b*16 + ch)*TT + j] = s;
}

// exclusive prefix over i (f32 accum), stored transposed fp16: FFT[b][j][i]
__global__ __launch_bounds__(256) void ff_pass2t(const float* __restrict__ SF,
                                                 const float* __restrict__ part,
                                                 __half* __restrict__ FFT)
{
  const int jg = blockIdx.x & 7, ch = (blockIdx.x >> 3) & 15, b = blockIdx.x >> 7;
  const int j = jg*256 + threadIdx.x;
  float acc = 0.f;
  for (int c = 0; c < ch; ++c) acc += part[(b*16 + c)*TT + j];
  const float* p = SF + ((size_t)b*TT + ch*128)*TT + j;
  __half* q = FFT + (size_t)b*TT*TT + (size_t)j*TT + ch*128;
  for (int i = 0; i < 128; ++i) {
    q[i] = __float2half_rn(acc);
    acc += p[(size_t)i*TT];
  }
}

// ---------------- per-tile FF minimum: minFF[b][jt32][ib32] ----------------
__global__ __launch_bounds__(256) void minff_k(const __half* __restrict__ FFT,
                                               float* __restrict__ minFF)
{
  const int b = blockIdx.x >> 6, ib = blockIdx.x & 63;
  const int tid = threadIdx.x;
  const __half* base = FFT + (size_t)b*TT*TT + (size_t)(tid*8)*TT + ib*32;
  float mn = INFINITY;
  #pragma unroll
  for (int e = 0; e < 8; ++e)
    mn = fminf(mn, __half2float(base[(size_t)e*TT]));
  mn = fminf(mn, __shfl_xor(mn, 1));
  mn = fminf(mn, __shfl_xor(mn, 2));
  if ((tid & 3) == 0)
    minFF[(b*64 + (tid >> 2))*64 + ib] = mn;
}

// ---------------- flash attention: swapped QK^T, FF-skip, FFT reads --------
// grid (bx=16, bh=32); block 4 waves x 32 q-rows = 128 rows.
__global__ __launch_bounds__(256) void flash_attn6(
    const ushort* __restrict__ qkvb, const __half* __restrict__ FFT,
    const float* __restrict__ minFF, ushort* __restrict__ Yb)
{
  const int bx = blockIdx.x;
  const int b = blockIdx.y >> 4, h = blockIdx.y & 15;
  const int tid = threadIdx.x, lane = tid & 63, wv = tid >> 6;
  const int hi = lane >> 5, lq = lane & 31;
  const int i0w = bx*128 + wv*32;            // wave's first q-row
  const int qg  = i0w + lq;                  // lane's q-row
  __shared__ __align__(16) ushort Vt[64][72];
  __shared__ short keep_list[32];
  __shared__ int s_nk;

  const int jtmax = 2*bx + 1;
  const int ibblk = bx*4;                    // i-block (32) index of block top
  if (tid < 64) {
    bool kp = false;
    if (tid <= jtmax) {
      const float m0 = minFF[(b*64 + 2*tid)*64 + ibblk];
      const float m1 = minFF[(b*64 + 2*tid + 1)*64 + ibblk];
      kp = fminf(m0, m1) <= FFTHR;
    }
    const unsigned long long mask = __ballot(kp);
    if (tid == 0) {
      int n = 0;
      unsigned long long m = mask;
      while (m) { keep_list[n++] = (short)__builtin_ctzll(m); m &= m - 1; }
      s_nk = n;
    }
  }

  bf16x8 qf[4];
  const ushort* qrow = qkvb + (size_t)(b*TT + qg)*N3 + h*HD + hi*8;
  #pragma unroll
  for (int dc = 0; dc < 4; ++dc) qf[dc] = *(const bf16x8*)(qrow + dc*16);

  f32x16 o0, o1;
  #pragma unroll
  for (int r = 0; r < 16; ++r) { o0[r] = 0.f; o1[r] = 0.f; }
  float m_run = -INFINITY, l_run = 0.f;

  const int vrow = tid & 63, vd = (tid >> 6) * 16;
  const ushort* gv0 = qkvb + (size_t)(b*TT + vrow)*N3 + 2*CC + h*HD + vd;

  __syncthreads();                           // keep_list ready
  const int nk = s_nk;
  bf16x8 u0, u1;
  {
    const size_t off = (size_t)keep_list[0]*64*N3;
    u0 = *(const bf16x8*)(gv0 + off);
    u1 = *(const bf16x8*)(gv0 + off + 8);
  }

  for (int idx = 0; idx < nk; ++idx) {
    const int jt = keep_list[idx];
    const int j0t = jt*64;
    bf16x8 kt[2][4];
    const bool wave_live = (j0t <= i0w + 31);   // wave-uniform
    if (wave_live) {
      #pragma unroll
      for (int js = 0; js < 2; ++js) {
        const ushort* kr = qkvb + (size_t)(b*TT + j0t + js*32 + lq)*N3 + CC + h*HD + hi*8;
        #pragma unroll
        for (int dc = 0; dc < 4; ++dc) kt[js][dc] = *(const bf16x8*)(kr + dc*16);
      }
    }
    __syncthreads();
    #pragma unroll
    for (int e = 0; e < 8; ++e) {
      Vt[vd + e][vrow]     = (ushort)u0[e];
      Vt[vd + 8 + e][vrow] = (ushort)u1[e];
    }
    __syncthreads();
    if (idx + 1 < nk) {
      const size_t off = (size_t)keep_list[idx+1]*64*N3;
      u0 = *(const bf16x8*)(gv0 + off);
      u1 = *(const bf16x8*)(gv0 + off + 8);
    }
    if (!wave_live) continue;

    #pragma unroll
    for (int jsub = 0; jsub < 2; ++jsub) {
      const int j0s = j0t + jsub*32;
      if (j0s > i0w + 31) continue;
      const float mw = minFF[(b*64 + (j0s >> 5))*64 + (i0w >> 5)];
      if (mw > FFTHR) continue;

      float ffv[16];
      {
        const __half* fft = FFT + (size_t)b*TT*TT + (size_t)j0s*TT + qg;
        #pragma unroll
        for (int r = 0; r < 16; ++r) {
          const int joff = (r&3) + 8*(r>>2) + 4*hi;
          ffv[r] = __half2float(fft[(size_t)joff*TT]);
        }
      }
      f32x16 st;
      #pragma unroll
      for (int r = 0; r < 16; ++r) st[r] = 0.f;
      #pragma unroll
      for (int dc = 0; dc < 4; ++dc)
        st = __builtin_amdgcn_mfma_f32_32x32x16_bf16(kt[jsub][dc], qf[dc], st, 0, 0, 0);

      float lg[16];
      float pmax = -INFINITY;
      const bool need_mask = (j0s + 31 > i0w);
      #pragma unroll
      for (int r = 0; r < 16; ++r) {
        float v = st[r]*0.125f - ffv[r];
        if (need_mask) {
          const int j = j0s + (r&3) + 8*(r>>2) + 4*hi;
          v = (j <= qg) ? v : -INFINITY;
        }
        lg[r] = v;
        pmax = fmaxf(pmax, v);
      }
      pmax = fmaxf(pmax, __shfl_xor(pmax, 32));
      if (!__all(pmax <= m_run)) {           // T13 defer-max
        const float mn = fmaxf(m_run, pmax);
        const float sc = __expf(m_run - mn);
        m_run = mn;
        l_run *= sc;
        #pragma unroll
        for (int r = 0; r < 16; ++r) {
          const float s0 = __shfl(sc, (r&3) + 8*(r>>2) + 4*hi);
          o0[r] *= s0; o1[r] *= s0;
        }
      }
      float rs = 0.f;
      #pragma unroll
      for (int r = 0; r < 16; ++r) {
        const float pe = __expf(lg[r] - m_run);
        lg[r] = pe;
        rs += pe;
      }
      rs += __shfl_xor(rs, 32);
      l_run += rs;
      uint32_t P8[8], Q8[8];
      #pragma unroll
      for (int g = 0; g < 4; ++g) {
        P8[2*g]   = cvt_pk_bf16(lg[4*g],   lg[4*g+1]);
        P8[2*g+1] = cvt_pk_bf16(lg[4*g+2], lg[4*g+3]);
      }
      #pragma unroll
      for (int k = 0; k < 8; ++k) Q8[k] = (uint32_t)__shfl_xor((int)P8[k], 32);
      #pragma unroll
      for (int mm = 0; mm < 2; ++mm) {
        pack4_t pk;
        pk.u[0] = hi ? Q8[4*mm+2] : P8[4*mm];
        pk.u[1] = hi ? Q8[4*mm+3] : P8[4*mm+1];
        pk.u[2] = hi ? P8[4*mm+2] : Q8[4*mm];
        pk.u[3] = hi ? P8[4*mm+3] : Q8[4*mm+1];
        const bf16x8 pa = pk.v;
        const bf16x8 v0 = *(const bf16x8*)&Vt[lq]     [jsub*32 + mm*16 + hi*8];
        const bf16x8 v1 = *(const bf16x8*)&Vt[32 + lq][jsub*32 + mm*16 + hi*8];
        o0 = __builtin_amdgcn_mfma_f32_32x32x16_bf16(pa, v0, o0, 0, 0, 0);
        o1 = __builtin_amdgcn_mfma_f32_32x32x16_bf16(pa, v1, o1, 0, 0, 0);
      }
    }
  }
  const float invl = 1.0f / l_run;
  #pragma unroll
  for (int r = 0; r < 16; ++r) {
    const int qm = (r&3) + 8*(r>>2) + 4*hi;
    const float il = __shfl(invl, qm);
    const size_t row = (size_t)(b*TT + i0w + qm)*CC + h*HD;
    Yb[row + lq]      = f2bf(o0[r] * il);
    Yb[row + 32 + lq] = f2bf(o1[r] * il);
  }
}

// ---------------------------------------------------------------------------
extern "C" void kernel_launch(void* const* d_in, const int* in_sizes, int n_in,
                              void* d_out, int out_size, void* d_ws, size_t ws_size,
                              hipStream_t stream) {
  const float* x      = (const float*)d_in[0];
  const float* w_attn = (const float*)d_in[1];
  const float* b_attn = (const float*)d_in[2];
  const float* w_proj = (const float*)d_in[3];
  const float* b_proj = (const float*)d_in[4];
  float* out = (float*)d_out;

  ushort* xb   = (ushort*)d_ws;                         // B*T*C bf16
  ushort* wab  = xb   + (size_t)BB*TT*CC;               // 3C*C bf16
  ushort* wpb  = wab  + (size_t)N3*CC;                  // C*C bf16
  ushort* qkvb = wpb  + (size_t)CC*CC;                  // B*T*3C bf16
  ushort* Yb   = qkvb + (size_t)BB*TT*N3;               // B*T*C bf16
  float*  SF   = (float*)(Yb + (size_t)BB*TT*CC);       // B*T*T f32 (S scores)
  float*  part = SF + (size_t)BB*TT*TT;                 // B*16*T f32
  __half* FFT  = (__half*)(part + (size_t)BB*16*TT);    // B*T*T fp16 transposed
  float*  minFF= (float*)(FFT + (size_t)BB*TT*TT);      // B*64*64 f32

  cast_bf16_k<<<(BB*TT*CC/4 + 255)/256, 256, 0, stream>>>(x, xb, BB*TT*CC);
  cast_bf16_k<<<(N3*CC/4 + 255)/256, 256, 0, stream>>>(w_attn, wab, N3*CC);
  cast_bf16_k<<<(CC*CC/4 + 255)/256, 256, 0, stream>>>(w_proj, wpb, CC*CC);

  gemm_lds<true><<<dim3(N3/128, (BB*TT)/128), 256, 0, stream>>>(
      xb, wab, b_attn, (void*)qkvb, BB*TT, N3, CC);

  hipMemsetAsync(SF, 0, (size_t)BB*TT*TT*sizeof(float), stream);
  s_scores_mfma<<<dim3(4, TT/64, BB), 256, 0, stream>>>(qkvb, SF);

  ff_pass1<<<256, 256, 0, stream>>>(SF, part);
  ff_pass2t<<<256, 256, 0, stream>>>(SF, part, FFT);
  minff_k<<<BB*64, 256, 0, stream>>>(FFT, minFF);

  flash_attn6<<<dim3(TT/128, BB*NH), 256, 0, stream>>>(qkvb, FFT, minFF, Yb);

  gemm_lds<false><<<dim3(CC/128, (BB*TT)/128), 256, 0, stream>>>(
      Yb, wpb, b_proj, (void*)out, BB*TT, CC, CC);
}

// Round 10
// 137.129 us; speedup vs baseline: 2.0274x; 1.2929x over previous
//
#include <hip/hip_runtime.h>
#include <hip/hip_fp16.h>
#include <stdint.h>
#include <math.h>

#define BB 2
#define TT 2048
#define CC 1024
#define NH 16
#define HD 64
#define N3 (3*CC)
#define NT (TT/64)
#define SPAD 74         // LDS row stride for 16x16-path kernels
#define FFTHR 24.0f     // skip tiles with min FF > 24: rel weight <= ~5e-7

typedef __attribute__((ext_vector_type(8)))  short bf16x8;
typedef __attribute__((ext_vector_type(4)))  float f32x4;
typedef __attribute__((ext_vector_type(16))) float f32x16;

__device__ inline ushort f2bf(float f) {
  uint32_t u = __float_as_uint(f);
  u += 0x7fff + ((u >> 16) & 1);          // RNE
  return (ushort)(u >> 16);
}
__device__ inline uint32_t cvt_pk_bf16(float lo, float hi_) {
  uint32_t r;
  asm("v_cvt_pk_bf16_f32 %0, %1, %2" : "=v"(r) : "v"(lo), "v"(hi_));
  return r;
}
__device__ inline float h2f(ushort u) {
  __half h = *reinterpret_cast<__half*>(&u);
  return __half2float(h);
}
__device__ inline ushort f2h(float f) {
  __half h = __float2half(f);
  return *reinterpret_cast<ushort*>(&h);
}

// direct global -> LDS staging, 16B per lane (dest = wave-uniform base + lane*16)
__device__ inline void gll16(const ushort* g, ushort* l) {
  __builtin_amdgcn_global_load_lds(
      (uint32_t __attribute__((address_space(1)))*)(g),
      (uint32_t __attribute__((address_space(3)))*)(l), 16, 0, 0);
}

typedef union { uint32_t u[4]; bf16x8 v; } pack4_t;

// ---------------- merged cast f32 -> bf16 for x, w_attn, w_proj ------------
__global__ __launch_bounds__(256) void cast3_k(
    const float* __restrict__ a, const float* __restrict__ b,
    const float* __restrict__ c, ushort* __restrict__ oa,
    ushort* __restrict__ ob, ushort* __restrict__ oc)
{
  const int n1 = BB*TT*CC, n2 = N3*CC;
  int i = (blockIdx.x * 256 + threadIdx.x) * 4;
  const float* src; ushort* dst;
  if (i < n1)           { src = a + i;            dst = oa + i; }
  else if (i < n1 + n2) { src = b + (i - n1);     dst = ob + (i - n1); }
  else                  { src = c + (i - n1 - n2); dst = oc + (i - n1 - n2); }
  float4 v = *(const float4*)src;
  ushort4 o;
  o.x = f2bf(v.x); o.y = f2bf(v.y); o.z = f2bf(v.z); o.w = f2bf(v.w);
  *(ushort4*)dst = o;
}

// ---------------- bf16 MFMA GEMM, global_load_lds staging ------------------
template<bool OUT_BF16>
__global__ __launch_bounds__(256) void gemm_lds(
    const ushort* __restrict__ A, const ushort* __restrict__ W,
    const float* __restrict__ bias, void* __restrict__ Cout,
    int M, int N, int K)
{
  __shared__ ushort As[128 * 32];
  __shared__ ushort Ws[128 * 32];
  const int tid = threadIdx.x;
  const int lane = tid & 63, wave = tid >> 6;
  const int wr = (wave >> 1) * 64, wc = (wave & 1) * 64;
  const int bm = blockIdx.y * 128, bn = blockIdx.x * 128;
  const int fr = lane & 15, kg = (lane >> 4) * 8, rg = (lane >> 4) * 4;

  const int srow = wave*32 + (lane >> 2);
  const int scol = (lane & 3) * 8;
  const ushort* ga0 = A + (size_t)(bm + srow) * K + scol;
  const ushort* ga1 = A + (size_t)(bm + srow + 16) * K + scol;
  const ushort* gw0 = W + (size_t)(bn + srow) * K + scol;
  const ushort* gw1 = W + (size_t)(bn + srow + 16) * K + scol;
  ushort* lA0 = &As[wave*1024];
  ushort* lA1 = &As[wave*1024 + 512];
  ushort* lW0 = &Ws[wave*1024];
  ushort* lW1 = &Ws[wave*1024 + 512];

  f32x4 acc[4][4];
  #pragma unroll
  for (int i=0;i<4;++i)
    #pragma unroll
    for (int j=0;j<4;++j) acc[i][j]=(f32x4){0.f,0.f,0.f,0.f};

  for (int k0 = 0; k0 < K; k0 += 32) {
    __syncthreads();
    gll16(ga0 + k0, lA0);
    gll16(ga1 + k0, lA1);
    gll16(gw0 + k0, lW0);
    gll16(gw1 + k0, lW1);
    __syncthreads();
    bf16x8 af[4], wf[4];
    #pragma unroll
    for (int m = 0; m < 4; ++m) af[m] = *(const bf16x8*)&As[(wr + m*16 + fr)*32 + kg];
    #pragma unroll
    for (int n = 0; n < 4; ++n) wf[n] = *(const bf16x8*)&Ws[(wc + n*16 + fr)*32 + kg];
    #pragma unroll
    for (int m = 0; m < 4; ++m)
      #pragma unroll
      for (int n = 0; n < 4; ++n)
        acc[m][n] = __builtin_amdgcn_mfma_f32_16x16x32_bf16(af[m], wf[n], acc[m][n], 0, 0, 0);
  }
  #pragma unroll
  for (int n = 0; n < 4; ++n) {
    const int col = bn + wc + n*16 + fr;
    const float bv = bias[col];
    #pragma unroll
    for (int m = 0; m < 4; ++m)
      #pragma unroll
      for (int r = 0; r < 4; ++r) {
        const int row = bm + wr + m*16 + rg + r;
        const float v = acc[m][n][r] + bv;
        if (OUT_BF16) ((ushort*)Cout)[(size_t)row * N + col] = f2bf(v);
        else          ((float*)Cout)[(size_t)row * N + col]  = v;
      }
  }
}

// ---------------- head-0 scores TRANSPOSED: ST[b][j][i] fp16 ---------------
// ST = mask(relu(q0.k0/8))^T via operand-swapped MFMA (A=K, B=Q).
__global__ __launch_bounds__(256) void s_scores_T(
    const ushort* __restrict__ qkvb, __half* __restrict__ ST)
{
  const int jc = blockIdx.x, it = blockIdx.y, b = blockIdx.z;
  if (jc * 8 > it) return;
  __shared__ ushort Qs[64 * SPAD], Ks[64 * SPAD];
  const int tid = threadIdx.x, lane = tid & 63, wave = tid >> 6;
  const int i0 = it * 64;
  const int fr = lane & 15, kg = (lane >> 4) * 8, rg = (lane >> 4) * 4;
  const int srow = tid >> 2, sd = (tid & 3) * 16;
  {
    const ushort* g = qkvb + (size_t)(b*TT + i0 + srow) * N3 + sd;   // head0 q
    bf16x8 v0 = *(const bf16x8*)g, v1 = *(const bf16x8*)(g + 8);
    *(bf16x8*)&Qs[srow*SPAD + sd]     = v0;
    *(bf16x8*)&Qs[srow*SPAD + sd + 8] = v1;
  }
  const int jt1 = min(jc*8 + 7, it);
  for (int jt = jc*8; jt <= jt1; ++jt) {
    const int j0 = jt * 64;
    __syncthreads();
    {
      const ushort* g = qkvb + (size_t)(b*TT + j0 + srow) * N3 + CC + sd;  // head0 k
      bf16x8 v0 = *(const bf16x8*)g, v1 = *(const bf16x8*)(g + 8);
      *(bf16x8*)&Ks[srow*SPAD + sd]     = v0;
      *(bf16x8*)&Ks[srow*SPAD + sd + 8] = v1;
    }
    __syncthreads();
    bf16x8 qf[2];
    #pragma unroll
    for (int kc = 0; kc < 2; ++kc) qf[kc] = *(const bf16x8*)&Qs[(wave*16 + fr)*SPAD + kc*32 + kg];
    #pragma unroll
    for (int n = 0; n < 4; ++n) {
      f32x4 s = (f32x4){0.f, 0.f, 0.f, 0.f};
      #pragma unroll
      for (int kc = 0; kc < 2; ++kc) {
        bf16x8 kf = *(const bf16x8*)&Ks[(n*16 + fr)*SPAD + kc*32 + kg];
        s = __builtin_amdgcn_mfma_f32_16x16x32_bf16(kf, qf[kc], s, 0, 0, 0);  // swapped
      }
      // C row = j (A=K rows), C col = i (B=Q rows)
      const int ig = i0 + wave*16 + fr;
      #pragma unroll
      for (int r = 0; r < 4; ++r) {
        const int jg = j0 + n*16 + rg + r;
        float v = s[r] * 0.125f;
        v = (jg < ig && jg != 0) ? fmaxf(v, 0.f) : 0.f;
        ST[((size_t)b*TT + jg)*TT + ig] = __float2half(v);
      }
    }
  }
}

// ---------------- fused exclusive row-scan (in place): ST -> FF^T ----------
// FF^T[b][j][i] = sum_{j < i' < i} ST[b][j][i'];  zeros for i <= j.
__global__ __launch_bounds__(256) void ff_scan(__half* __restrict__ SFH)
{
  const int wv = threadIdx.x >> 6, lane = threadIdx.x & 63;
  const int row = blockIdx.x*4 + wv;
  const int b = row >> 11, jj = row & (TT-1);
  ushort* p = (ushort*)(SFH + ((size_t)b*TT + jj)*TT);
  float acc = 0.f;
  #pragma unroll
  for (int it = 0; it < 4; ++it) {
    const int i0 = it*512 + lane*8;
    bf16x8 raw = *(const bf16x8*)(p + i0);
    float e[8];
    float lsum = 0.f;
    #pragma unroll
    for (int k = 0; k < 8; ++k) {
      const float v = h2f((ushort)raw[k]);
      e[k] = (i0 + k > jj) ? v : 0.f;
      lsum += e[k];
    }
    float sc = lsum;
    #pragma unroll
    for (int off = 1; off < 64; off <<= 1) {
      const float t = __shfl_up(sc, off);
      if (lane >= off) sc += t;
    }
    float pr = acc + (sc - lsum);        // exclusive across lanes
    bf16x8 o;
    #pragma unroll
    for (int k = 0; k < 8; ++k) {
      o[k] = (short)f2h(pr);
      pr += e[k];
    }
    *(bf16x8*)(p + i0) = o;
    acc += __shfl(sc, 63);               // wave total
  }
}

// ---------------- per-tile FF minimum: minFF[b][jt32][ib32] ----------------
__global__ __launch_bounds__(256) void minff_k(const __half* __restrict__ FFT,
                                               float* __restrict__ minFF)
{
  const int b = blockIdx.x >> 6, ib = blockIdx.x & 63;
  const int tid = threadIdx.x;
  const __half* base = FFT + (size_t)b*TT*TT + (size_t)(tid*8)*TT + ib*32;
  float mn = INFINITY;
  #pragma unroll
  for (int e = 0; e < 8; ++e)
    mn = fminf(mn, __half2float(base[(size_t)e*TT]));
  mn = fminf(mn, __shfl_xor(mn, 1));
  mn = fminf(mn, __shfl_xor(mn, 2));
  if ((tid & 3) == 0)
    minFF[(b*64 + (tid >> 2))*64 + ib] = mn;
}

// ---------------- flash attention: swapped QK^T, FF-skip, big-first --------
// 1D grid 512: bx = 15 - bid/32 (heavy blocks first), bh = bid & 31.
__global__ __launch_bounds__(256) void flash_attn7(
    const ushort* __restrict__ qkvb, const __half* __restrict__ FFT,
    const float* __restrict__ minFF, ushort* __restrict__ Yb)
{
  const int bid = blockIdx.x;
  const int bx = 15 - (bid >> 5);
  const int bh = bid & 31;
  const int b = bh >> 4, h = bh & 15;
  const int tid = threadIdx.x, lane = tid & 63, wv = tid >> 6;
  const int hi = lane >> 5, lq = lane & 31;
  const int i0w = bx*128 + wv*32;
  const int qg  = i0w + lq;
  __shared__ __align__(16) ushort Vt[64][72];
  __shared__ short keep_list[32];
  __shared__ int s_nk;

  const int jtmax = 2*bx + 1;
  const int ibblk = bx*4;
  if (tid < 64) {
    bool kp = false;
    if (tid <= jtmax) {
      const float m0 = minFF[(b*64 + 2*tid)*64 + ibblk];
      const float m1 = minFF[(b*64 + 2*tid + 1)*64 + ibblk];
      kp = fminf(m0, m1) <= FFTHR;
    }
    const unsigned long long mask = __ballot(kp);
    if (tid == 0) {
      int n = 0;
      unsigned long long m = mask;
      while (m) { keep_list[n++] = (short)__builtin_ctzll(m); m &= m - 1; }
      s_nk = n;
    }
  }

  bf16x8 qf[4];
  const ushort* qrow = qkvb + (size_t)(b*TT + qg)*N3 + h*HD + hi*8;
  #pragma unroll
  for (int dc = 0; dc < 4; ++dc) qf[dc] = *(const bf16x8*)(qrow + dc*16);

  f32x16 o0, o1;
  #pragma unroll
  for (int r = 0; r < 16; ++r) { o0[r] = 0.f; o1[r] = 0.f; }
  float m_run = -INFINITY, l_run = 0.f;

  const int vrow = tid & 63, vd = (tid >> 6) * 16;
  const ushort* gv0 = qkvb + (size_t)(b*TT + vrow)*N3 + 2*CC + h*HD + vd;

  __syncthreads();                           // keep_list ready
  const int nk = s_nk;
  bf16x8 u0, u1;
  {
    const size_t off = (size_t)keep_list[0]*64*N3;
    u0 = *(const bf16x8*)(gv0 + off);
    u1 = *(const bf16x8*)(gv0 + off + 8);
  }

  for (int idx = 0; idx < nk; ++idx) {
    const int jt = keep_list[idx];
    const int j0t = jt*64;
    bf16x8 kt[2][4];
    const bool wave_live = (j0t <= i0w + 31);
    if (wave_live) {
      #pragma unroll
      for (int js = 0; js < 2; ++js) {
        const ushort* kr = qkvb + (size_t)(b*TT + j0t + js*32 + lq)*N3 + CC + h*HD + hi*8;
        #pragma unroll
        for (int dc = 0; dc < 4; ++dc) kt[js][dc] = *(const bf16x8*)(kr + dc*16);
      }
    }
    __syncthreads();
    #pragma unroll
    for (int e = 0; e < 8; ++e) {
      Vt[vd + e][vrow]     = (ushort)u0[e];
      Vt[vd + 8 + e][vrow] = (ushort)u1[e];
    }
    __syncthreads();
    if (idx + 1 < nk) {
      const size_t off = (size_t)keep_list[idx+1]*64*N3;
      u0 = *(const bf16x8*)(gv0 + off);
      u1 = *(const bf16x8*)(gv0 + off + 8);
    }
    if (!wave_live) continue;

    #pragma unroll
    for (int jsub = 0; jsub < 2; ++jsub) {
      const int j0s = j0t + jsub*32;
      if (j0s > i0w + 31) continue;
      const float mw = minFF[(b*64 + (j0s >> 5))*64 + (i0w >> 5)];
      if (mw > FFTHR) continue;

      float ffv[16];
      {
        const __half* fft = FFT + (size_t)b*TT*TT + (size_t)j0s*TT + qg;
        #pragma unroll
        for (int r = 0; r < 16; ++r) {
          const int joff = (r&3) + 8*(r>>2) + 4*hi;
          ffv[r] = __half2float(fft[(size_t)joff*TT]);
        }
      }
      f32x16 st;
      #pragma unroll
      for (int r = 0; r < 16; ++r) st[r] = 0.f;
      #pragma unroll
      for (int dc = 0; dc < 4; ++dc)
        st = __builtin_amdgcn_mfma_f32_32x32x16_bf16(kt[jsub][dc], qf[dc], st, 0, 0, 0);

      float lg[16];
      float pmax = -INFINITY;
      const bool need_mask = (j0s + 31 > i0w);
      #pragma unroll
      for (int r = 0; r < 16; ++r) {
        float v = st[r]*0.125f - ffv[r];
        if (need_mask) {
          const int j = j0s + (r&3) + 8*(r>>2) + 4*hi;
          v = (j <= qg) ? v : -INFINITY;
        }
        lg[r] = v;
        pmax = fmaxf(pmax, v);
      }
      pmax = fmaxf(pmax, __shfl_xor(pmax, 32));
      if (!__all(pmax <= m_run)) {           // T13 defer-max
        const float mn = fmaxf(m_run, pmax);
        const float sc = __expf(m_run - mn);
        m_run = mn;
        l_run *= sc;
        #pragma unroll
        for (int r = 0; r < 16; ++r) {
          const float s0 = __shfl(sc, (r&3) + 8*(r>>2) + 4*hi);
          o0[r] *= s0; o1[r] *= s0;
        }
      }
      float rs = 0.f;
      #pragma unroll
      for (int r = 0; r < 16; ++r) {
        const float pe = __expf(lg[r] - m_run);
        lg[r] = pe;
        rs += pe;
      }
      rs += __shfl_xor(rs, 32);
      l_run += rs;
      uint32_t P8[8], Q8[8];
      #pragma unroll
      for (int g = 0; g < 4; ++g) {
        P8[2*g]   = cvt_pk_bf16(lg[4*g],   lg[4*g+1]);
        P8[2*g+1] = cvt_pk_bf16(lg[4*g+2], lg[4*g+3]);
      }
      #pragma unroll
      for (int k = 0; k < 8; ++k) Q8[k] = (uint32_t)__shfl_xor((int)P8[k], 32);
      #pragma unroll
      for (int mm = 0; mm < 2; ++mm) {
        pack4_t pk;
        pk.u[0] = hi ? Q8[4*mm+2] : P8[4*mm];
        pk.u[1] = hi ? Q8[4*mm+3] : P8[4*mm+1];
        pk.u[2] = hi ? P8[4*mm+2] : Q8[4*mm];
        pk.u[3] = hi ? P8[4*mm+3] : Q8[4*mm+1];
        const bf16x8 pa = pk.v;
        const bf16x8 v0 = *(const bf16x8*)&Vt[lq]     [jsub*32 + mm*16 + hi*8];
        const bf16x8 v1 = *(const bf16x8*)&Vt[32 + lq][jsub*32 + mm*16 + hi*8];
        o0 = __builtin_amdgcn_mfma_f32_32x32x16_bf16(pa, v0, o0, 0, 0, 0);
        o1 = __builtin_amdgcn_mfma_f32_32x32x16_bf16(pa, v1, o1, 0, 0, 0);
      }
    }
  }
  const float invl = 1.0f / l_run;
  #pragma unroll
  for (int r = 0; r < 16; ++r) {
    const int qm = (r&3) + 8*(r>>2) + 4*hi;
    const float il = __shfl(invl, qm);
    const size_t row = (size_t)(b*TT + i0w + qm)*CC + h*HD;
    Yb[row + lq]      = f2bf(o0[r] * il);
    Yb[row + 32 + lq] = f2bf(o1[r] * il);
  }
}

// ---------------------------------------------------------------------------
extern "C" void kernel_launch(void* const* d_in, const int* in_sizes, int n_in,
                              void* d_out, int out_size, void* d_ws, size_t ws_size,
                              hipStream_t stream) {
  const float* x      = (const float*)d_in[0];
  const float* w_attn = (const float*)d_in[1];
  const float* b_attn = (const float*)d_in[2];
  const float* w_proj = (const float*)d_in[3];
  const float* b_proj = (const float*)d_in[4];
  float* out = (float*)d_out;

  ushort* xb   = (ushort*)d_ws;                         // B*T*C bf16
  ushort* wab  = xb   + (size_t)BB*TT*CC;               // 3C*C bf16
  ushort* wpb  = wab  + (size_t)N3*CC;                  // C*C bf16
  ushort* qkvb = wpb  + (size_t)CC*CC;                  // B*T*3C bf16
  ushort* Yb   = qkvb + (size_t)BB*TT*N3;               // B*T*C bf16
  __half* SFH  = (__half*)(Yb + (size_t)BB*TT*CC);      // B*T*T fp16 (S^T -> FF^T)
  float*  minFF= (float*)(SFH + (size_t)BB*TT*TT);      // B*64*64 f32

  const int ntot4 = (BB*TT*CC + N3*CC + CC*CC) / 4;
  cast3_k<<<(ntot4 + 255)/256, 256, 0, stream>>>(x, w_attn, w_proj, xb, wab, wpb);

  gemm_lds<true><<<dim3(N3/128, (BB*TT)/128), 256, 0, stream>>>(
      xb, wab, b_attn, (void*)qkvb, BB*TT, N3, CC);

  s_scores_T<<<dim3(4, TT/64, BB), 256, 0, stream>>>(qkvb, SFH);
  ff_scan<<<(BB*TT)/4, 256, 0, stream>>>(SFH);
  minff_k<<<BB*64, 256, 0, stream>>>(SFH, minFF);

  flash_attn7<<<512, 256, 0, stream>>>(qkvb, SFH, minFF, Yb);

  gemm_lds<false><<<dim3(CC/128, (BB*TT)/128), 256, 0, stream>>>(
      Yb, wpb, b_proj, (void*)out, BB*TT, CC, CC);
}